// Round 1
// baseline (527.104 us; speedup 1.0000x reference)
//
#include <hip/hip_runtime.h>

// Problem constants (fixed by the reference)
constexpr int NB  = 8;
constexpr int NC  = 64;
constexpr int NH  = 128;
constexpr int NW  = 128;
constexpr int NHW = NH * NW;          // 16384
constexpr int CHW = NC * NHW;         // 1048576
constexpr int SZ  = NB * CHW;         // 8388608 elements per tensor
constexpr int NPOS = NB * NHW;        // 131072 spatial positions
constexpr float EPS = 1e-5f;

// ---------------------------------------------------------------------------
// (B,N,C) -> (B,C,H,W) transpose, LDS-tiled, coalesced both sides
__global__ void k_transpose(const float* __restrict__ x, float* __restrict__ xn) {
    __shared__ float t[64 * 65];
    int b   = blockIdx.x >> 8;            // 256 tiles of 64 positions per b
    int hw0 = (blockIdx.x & 255) << 6;
    int tid = threadIdx.x;
    #pragma unroll
    for (int k = 0; k < 16; ++k) {
        int idx = tid + (k << 8);
        int c = idx & 63, hwl = idx >> 6;
        t[c * 65 + hwl] = x[((size_t)b * NHW + hw0 + hwl) * NC + c];
    }
    __syncthreads();
    #pragma unroll
    for (int k = 0; k < 16; ++k) {
        int idx = tid + (k << 8);
        int hwl = idx & 63, c = idx >> 6;
        xn[(size_t)(b * NC + c) * NHW + hw0 + hwl] = t[c * 65 + hwl];
    }
}

// ---------------------------------------------------------------------------
// Rolled channel-linear: out[b,d,h,w] = act( sum_c in[b,c,roll(h,w,c)] * W + bias ) [+ xn]
// MODE 0: rollH (h-c)%H   (used by fc1, fc4 inputs)
// MODE 1: rollW (w-c)%W   (fc2 input)
// MODE 2: rollW (w+c)%W   (fc3 input)
// MODE 3: no roll         (pointwise conv)
// WTRANS: weight indexed [d][c] (pc_w) instead of [c][d] (fc*)
template<int MODE, bool GELU_OUT, bool ADDXN, bool WTRANS, bool HASBIAS>
__global__ void k_fc(const float* __restrict__ in, const float* __restrict__ wgt,
                     const float* __restrict__ bias, const float* __restrict__ xn,
                     float* __restrict__ out) {
    __shared__ float wl[64 * 65];   // padded; only used with stride 65 when WTRANS
    int tid = threadIdx.x;
    if (WTRANS) {
        #pragma unroll
        for (int k = 0; k < 16; ++k) {
            int idx = tid + (k << 8);
            int o = idx >> 6, cc = idx & 63;
            wl[cc * 65 + o] = wgt[idx];   // store transposed, pad avoids bank conflicts
        }
    } else {
        #pragma unroll
        for (int k = 0; k < 16; ++k) {
            int idx = tid + (k << 8);
            wl[idx] = wgt[idx];
        }
    }
    __syncthreads();

    int p  = blockIdx.x * 256 + tid;      // 0 .. NPOS-1
    int b  = p >> 14;
    int hw = p & (NHW - 1);
    int h  = hw >> 7, w = hw & 127;

    float acc[64];
    #pragma unroll
    for (int d = 0; d < 64; ++d) acc[d] = 0.f;

    const float* inb = in + (size_t)b * CHW;
    constexpr int LDW = WTRANS ? 65 : 64;

    for (int c = 0; c < 64; ++c) {
        int addr;
        if (MODE == 0)      addr = c * NHW + (((h - c) & 127) << 7) + w;
        else if (MODE == 1) addr = c * NHW + (h << 7) + ((w - c) & 127);
        else if (MODE == 2) addr = c * NHW + (h << 7) + ((w + c) & 127);
        else                addr = c * NHW + hw;
        float v = inb[addr];
        #pragma unroll
        for (int d = 0; d < 64; ++d)
            acc[d] += v * wl[c * LDW + d];
    }

    size_t obase = (size_t)b * CHW + hw;
    #pragma unroll
    for (int d = 0; d < 64; ++d) {
        float r = acc[d];
        if (HASBIAS) r += bias[d];
        if (GELU_OUT) r = 0.5f * r * (1.f + erff(r * 0.70710678118654752f));
        if (ADDXN)   r += xn[obase + (size_t)d * NHW];
        out[obase + (size_t)d * NHW] = r;
    }
}

// ---------------------------------------------------------------------------
// LayerNorm over concat(x_1,x_2) channel dim (128) + fc5 (128->64) + bias + xn
__global__ void k_ln_fc5(const float* __restrict__ x1p, const float* __restrict__ x2p,
                         const float* __restrict__ ln_g, const float* __restrict__ ln_b,
                         const float* __restrict__ w5, const float* __restrict__ b5,
                         const float* __restrict__ xn, float* __restrict__ out) {
    __shared__ float wl[128 * 64];
    __shared__ float gl[128], bl[128];
    int tid = threadIdx.x;
    #pragma unroll
    for (int k = 0; k < 32; ++k) wl[tid + (k << 8)] = w5[tid + (k << 8)];
    if (tid < 128) { gl[tid] = ln_g[tid]; bl[tid] = ln_b[tid]; }
    __syncthreads();

    int p  = blockIdx.x * 256 + tid;
    int b  = p >> 14;
    int hw = p & (NHW - 1);
    const float* a1 = x1p + (size_t)b * CHW + hw;
    const float* a2 = x2p + (size_t)b * CHW + hw;

    float s = 0.f, sq = 0.f;
    for (int c = 0; c < 64; ++c) { float v = a1[(size_t)c * NHW]; s += v; sq += v * v; }
    for (int c = 0; c < 64; ++c) { float v = a2[(size_t)c * NHW]; s += v; sq += v * v; }
    float m    = s * (1.f / 128.f);
    float var  = sq * (1.f / 128.f) - m * m;
    float rstd = rsqrtf(var + EPS);

    float acc[64];
    #pragma unroll
    for (int d = 0; d < 64; ++d) acc[d] = 0.f;

    for (int c = 0; c < 64; ++c) {
        float vn = (a1[(size_t)c * NHW] - m) * rstd * gl[c] + bl[c];
        #pragma unroll
        for (int d = 0; d < 64; ++d) acc[d] += vn * wl[c * 64 + d];
    }
    for (int c = 0; c < 64; ++c) {
        float vn = (a2[(size_t)c * NHW] - m) * rstd * gl[64 + c] + bl[64 + c];
        #pragma unroll
        for (int d = 0; d < 64; ++d) acc[d] += vn * wl[(64 + c) * 64 + d];
    }

    size_t obase = (size_t)b * CHW + hw;
    #pragma unroll
    for (int d = 0; d < 64; ++d)
        out[obase + (size_t)d * NHW] = acc[d] + b5[d] + xn[obase + (size_t)d * NHW];
}

// ---------------------------------------------------------------------------
// Depthwise 3x3 conv, dilation DIL, zero pad = DIL (cross-correlation, XLA semantics)
template<int DIL, bool HASBIAS>
__global__ void k_dwconv(const float* __restrict__ in, const float* __restrict__ wgt,
                         const float* __restrict__ bias, float* __restrict__ out) {
    int p = blockIdx.x * 256 + threadIdx.x;   // over SZ
    int w = p & 127, h = (p >> 7) & 127, c = (p >> 14) & 63;
    const float* ib = in + (size_t)(p >> 14) * NHW;   // (b*C+c) plane
    const float* wc = wgt + c * 9;
    float acc = HASBIAS ? bias[c] : 0.f;
    #pragma unroll
    for (int i = 0; i < 3; ++i) {
        int hh = h + (i - 1) * DIL;
        if (hh < 0 || hh >= NH) continue;
        #pragma unroll
        for (int j = 0; j < 3; ++j) {
            int ww = w + (j - 1) * DIL;
            if (ww < 0 || ww >= NW) continue;
            acc += ib[hh * NW + ww] * wc[i * 3 + j];
        }
    }
    out[p] = acc;
}

// ---------------------------------------------------------------------------
// Per-(b,c) plane sum and sumsq (for BN training-mode stats), block per plane
__global__ void k_plane_stats(const float* __restrict__ in,
                              float* __restrict__ psum, float* __restrict__ psq) {
    __shared__ float ss[256], sq[256];
    int bc = blockIdx.x, tid = threadIdx.x;
    const float* pl = in + (size_t)bc * NHW;
    float s = 0.f, q = 0.f;
    for (int i = tid; i < NHW; i += 256) { float v = pl[i]; s += v; q += v * v; }
    ss[tid] = s; sq[tid] = q; __syncthreads();
    for (int o = 128; o > 0; o >>= 1) {
        if (tid < o) { ss[tid] += ss[tid + o]; sq[tid] += sq[tid + o]; }
        __syncthreads();
    }
    if (tid == 0) { psum[bc] = ss[0]; psq[bc] = sq[0]; }
}

__global__ void k_bn_finalize(const float* __restrict__ psum, const float* __restrict__ psq,
                              float* __restrict__ meanc, float* __restrict__ rstdc) {
    int c = threadIdx.x;  // 64 threads
    float s = 0.f, q = 0.f;
    for (int b = 0; b < NB; ++b) { s += psum[b * 64 + c]; q += psq[b * 64 + c]; }
    const float inv = 1.f / (float)(NB * NHW);
    float m = s * inv;
    float v = q * inv - m * m;
    meanc[c] = m;
    rstdc[c] = rsqrtf(v + EPS);
}

__global__ void k_bn_relu(const float* __restrict__ in, const float* __restrict__ meanc,
                          const float* __restrict__ rstdc, const float* __restrict__ g,
                          const float* __restrict__ bb, float* __restrict__ out) {
    int p = blockIdx.x * 256 + threadIdx.x;
    int c = (p >> 14) & 63;
    float v = (in[p] - meanc[c]) * rstdc[c] * g[c] + bb[c];
    out[p] = v > 0.f ? v : 0.f;
}

// ---------------------------------------------------------------------------
// SE: s[b,c] = mean_{hw} 4*x2*y3 ; block per (b,c)
__global__ void k_se_reduce(const float* __restrict__ x2, const float* __restrict__ y3,
                            float* __restrict__ s) {
    __shared__ float ss[256];
    int bc = blockIdx.x, tid = threadIdx.x;
    const float* a  = x2 + (size_t)bc * NHW;
    const float* b_ = y3 + (size_t)bc * NHW;
    float acc = 0.f;
    for (int i = tid; i < NHW; i += 256) acc += a[i] * b_[i];
    ss[tid] = acc; __syncthreads();
    for (int o = 128; o > 0; o >>= 1) {
        if (tid < o) ss[tid] += ss[tid + o];
        __syncthreads();
    }
    if (tid == 0) s[bc] = ss[0] * (4.f / (float)NHW);
}

// e[b,c] = sigmoid(W2 @ relu(W1 @ s + b1) + b2) ; one block (64 threads) per b
__global__ void k_se_mlp(const float* __restrict__ s, const float* __restrict__ w1,
                         const float* __restrict__ b1, const float* __restrict__ w2,
                         const float* __restrict__ b2, float* __restrict__ e) {
    __shared__ float sh[64], e1[8];
    int b = blockIdx.x, tid = threadIdx.x;
    sh[tid] = s[b * 64 + tid];
    __syncthreads();
    if (tid < 8) {
        float a = b1[tid];
        for (int c = 0; c < 64; ++c) a += sh[c] * w1[tid * 64 + c];
        e1[tid] = a > 0.f ? a : 0.f;
    }
    __syncthreads();
    float a = b2[tid];
    #pragma unroll
    for (int j = 0; j < 8; ++j) a += e1[j] * w2[tid * 8 + j];
    e[b * 64 + tid] = 1.f / (1.f + expf(-a));
}

// out = x7 * (1 + e), x7 = 4*x2*y3
__global__ void k_final(const float* __restrict__ x2, const float* __restrict__ y3,
                        const float* __restrict__ e, float* __restrict__ out) {
    int p = blockIdx.x * 256 + threadIdx.x;
    int b = p >> 20, c = (p >> 14) & 63;
    out[p] = 4.f * x2[p] * y3[p] * (1.f + e[b * 64 + c]);
}

// ---------------------------------------------------------------------------
extern "C" void kernel_launch(void* const* d_in, const int* in_sizes, int n_in,
                              void* d_out, int out_size, void* d_ws, size_t ws_size,
                              hipStream_t stream) {
    const float* x     = (const float*)d_in[0];
    const float* fc1w  = (const float*)d_in[1];
    const float* fc1b  = (const float*)d_in[2];
    const float* fc2w  = (const float*)d_in[3];
    const float* fc2b  = (const float*)d_in[4];
    const float* fc3w  = (const float*)d_in[5];
    const float* fc3b  = (const float*)d_in[6];
    const float* fc4w  = (const float*)d_in[7];
    const float* fc4b  = (const float*)d_in[8];
    const float* fc5w  = (const float*)d_in[9];
    const float* fc5b  = (const float*)d_in[10];
    const float* lng   = (const float*)d_in[11];
    const float* lnb   = (const float*)d_in[12];
    const float* pcw   = (const float*)d_in[13];
    const float* dww   = (const float*)d_in[14];
    const float* dwb   = (const float*)d_in[15];
    const float* dwbng = (const float*)d_in[16];
    const float* dwbnb = (const float*)d_in[17];
    const float* ddw   = (const float*)d_in[18];
    const float* ddbng = (const float*)d_in[19];
    const float* ddbnb = (const float*)d_in[20];
    const float* sew1  = (const float*)d_in[21];
    const float* seb1  = (const float*)d_in[22];
    const float* sew2  = (const float*)d_in[23];
    const float* seb2  = (const float*)d_in[24];

    float* out  = (float*)d_out;
    float* ws   = (float*)d_ws;
    float* buf0 = ws;                      // xn, later x2
    float* buf1 = ws + (size_t)SZ;         // t1, x_2, d1, d2, y3
    float* buf2 = ws + (size_t)2 * SZ;     // t2, x1, y, y2
    float* st   = ws + (size_t)3 * SZ;
    float* psum  = st;          // 512
    float* psq   = st + 512;    // 512
    float* meanc = st + 1024;   // 64
    float* rstdc = st + 1088;   // 64
    float* svec  = st + 1152;   // 512
    float* evec  = st + 1664;   // 512

    dim3 blk(256);

    // xn = transpose(x)
    k_transpose<<<NB * (NHW / 64), blk, 0, stream>>>(x, buf0);
    // t1 = gelu(fc1(roll_h(xn,+1)))
    k_fc<0, true,  false, false, true><<<NPOS / 256, blk, 0, stream>>>(buf0, fc1w, fc1b, nullptr, buf1);
    // t2 = gelu(fc3(roll_w(xn,-1)))
    k_fc<2, true,  false, false, true><<<NPOS / 256, blk, 0, stream>>>(buf0, fc3w, fc3b, nullptr, buf2);
    // x_1 = fc2(roll_w(t1,+1)) + xn   (d_out used as scratch, fully rewritten later)
    k_fc<1, false, true,  false, true><<<NPOS / 256, blk, 0, stream>>>(buf1, fc2w, fc2b, buf0, out);
    // x_2 = fc4(roll_h(t2,+1)) + xn
    k_fc<0, false, true,  false, true><<<NPOS / 256, blk, 0, stream>>>(buf2, fc4w, fc4b, buf0, buf1);
    // x1 = LN(concat(x_1,x_2)) @ fc5 + b5 + xn
    k_ln_fc5<<<NPOS / 256, blk, 0, stream>>>(out, buf1, lng, lnb, fc5w, fc5b, buf0, buf2);
    // x2 = pc(x1)
    k_fc<3, false, false, true, false><<<NPOS / 256, blk, 0, stream>>>(buf2, pcw, nullptr, nullptr, buf0);
    // d1 = dwconv3x3(x2, dil=1) + dw_b
    k_dwconv<1, true><<<SZ / 256, blk, 0, stream>>>(buf0, dww, dwb, buf1);
    k_plane_stats<<<NB * NC, blk, 0, stream>>>(buf1, psum, psq);
    k_bn_finalize<<<1, 64, 0, stream>>>(psum, psq, meanc, rstdc);
    // y = relu(bn(d1))
    k_bn_relu<<<SZ / 256, blk, 0, stream>>>(buf1, meanc, rstdc, dwbng, dwbnb, buf2);
    // d2 = dwconv3x3(y, dil=2)
    k_dwconv<2, false><<<SZ / 256, blk, 0, stream>>>(buf2, ddw, nullptr, buf1);
    k_plane_stats<<<NB * NC, blk, 0, stream>>>(buf1, psum, psq);
    k_bn_finalize<<<1, 64, 0, stream>>>(psum, psq, meanc, rstdc);
    // y2 = relu(bn(d2))
    k_bn_relu<<<SZ / 256, blk, 0, stream>>>(buf1, meanc, rstdc, ddbng, ddbnb, buf2);
    // y3 = pc(y2)
    k_fc<3, false, false, true, false><<<NPOS / 256, blk, 0, stream>>>(buf2, pcw, nullptr, nullptr, buf1);
    // SE + final: out = 4*x2*y3*(1+e)
    k_se_reduce<<<NB * NC, blk, 0, stream>>>(buf0, buf1, svec);
    k_se_mlp<<<NB, 64, 0, stream>>>(svec, sew1, seb1, sew2, seb2, evec);
    k_final<<<SZ / 256, blk, 0, stream>>>(buf0, buf1, evec, out);
}

// Round 2
// 512.098 us; speedup vs baseline: 1.0293x; 1.0293x over previous
//
#include <hip/hip_runtime.h>

// Problem constants (fixed by the reference)
constexpr int NB  = 8;
constexpr int NC  = 64;
constexpr int NH  = 128;
constexpr int NW  = 128;
constexpr int NHW = NH * NW;          // 16384
constexpr int CHW = NC * NHW;         // 1048576
constexpr int SZ  = NB * CHW;         // 8388608 elements per tensor
constexpr int NPOS = NB * NHW;        // 131072 spatial positions
constexpr float EPS = 1e-5f;

// ---------------------------------------------------------------------------
// (B,N,C) -> (B,C,H,W) transpose, LDS-tiled, coalesced both sides
__global__ void k_transpose(const float* __restrict__ x, float* __restrict__ xn) {
    __shared__ float t[64 * 65];
    int b   = blockIdx.x >> 8;            // 256 tiles of 64 positions per b
    int hw0 = (blockIdx.x & 255) << 6;
    int tid = threadIdx.x;
    #pragma unroll
    for (int k = 0; k < 16; ++k) {
        int idx = tid + (k << 8);
        int c = idx & 63, hwl = idx >> 6;
        t[c * 65 + hwl] = x[((size_t)b * NHW + hw0 + hwl) * NC + c];
    }
    __syncthreads();
    #pragma unroll
    for (int k = 0; k < 16; ++k) {
        int idx = tid + (k << 8);
        int hwl = idx & 63, c = idx >> 6;
        xn[(size_t)(b * NC + c) * NHW + hw0 + hwl] = t[c * 65 + hwl];
    }
}

// ---------------------------------------------------------------------------
// Rolled channel-linear, CHUNKED accumulator (4 x 16 outputs per thread; no spill).
// MODE 0: rollH (h-c)%H | 1: rollW (w-c)%W | 2: rollW (w+c)%W | 3: no roll
// WTRANS: weight indexed [d][c] (pc_w) instead of [c][d] (fc*)
// BNRELU_IN: apply per-channel affine (BN) + relu to loaded input values
template<int MODE, bool GELU_OUT, bool ADDXN, bool WTRANS, bool HASBIAS, bool BNRELU_IN>
__global__ void k_fc(const float* __restrict__ in, const float* __restrict__ wgt,
                     const float* __restrict__ bias, const float* __restrict__ xn,
                     const float* __restrict__ meanc, const float* __restrict__ rstdc,
                     const float* __restrict__ bng, const float* __restrict__ bnb,
                     float* __restrict__ out) {
    __shared__ float wl[64 * 65];       // stride 65 only used when WTRANS
    __shared__ float scl[64], sft[64];
    int tid = threadIdx.x;
    if (WTRANS) {
        #pragma unroll
        for (int k = 0; k < 16; ++k) {
            int idx = tid + (k << 8);
            int o = idx >> 6, cc = idx & 63;
            wl[cc * 65 + o] = wgt[idx];   // store transposed, padded
        }
    } else {
        #pragma unroll
        for (int k = 0; k < 16; ++k) {
            int idx = tid + (k << 8);
            wl[idx] = wgt[idx];
        }
    }
    if (BNRELU_IN && tid < 64) {
        float s = rstdc[tid] * bng[tid];
        scl[tid] = s;
        sft[tid] = bnb[tid] - meanc[tid] * s;
    }
    __syncthreads();

    int p  = blockIdx.x * 256 + tid;      // 0 .. NPOS-1
    int b  = p >> 14;
    int hw = p & (NHW - 1);
    int h  = hw >> 7, w = hw & 127;

    const float* inb = in + (size_t)b * CHW;
    size_t obase = (size_t)b * CHW + hw;
    constexpr int LDW = WTRANS ? 65 : 64;

    #pragma unroll 1
    for (int chunk = 0; chunk < 4; ++chunk) {
        float acc[16];
        #pragma unroll
        for (int d = 0; d < 16; ++d) acc[d] = 0.f;

        for (int c = 0; c < 64; ++c) {
            int addr;
            if (MODE == 0)      addr = c * NHW + (((h - c) & 127) << 7) + w;
            else if (MODE == 1) addr = c * NHW + (h << 7) + ((w - c) & 127);
            else if (MODE == 2) addr = c * NHW + (h << 7) + ((w + c) & 127);
            else                addr = c * NHW + hw;
            float v = inb[addr];
            if (BNRELU_IN) { v = fmaxf(v * scl[c] + sft[c], 0.f); }
            const float* wrow = &wl[c * LDW + chunk * 16];
            #pragma unroll
            for (int d = 0; d < 16; ++d)
                acc[d] += v * wrow[d];
        }

        #pragma unroll
        for (int d = 0; d < 16; ++d) {
            int dd = chunk * 16 + d;
            float r = acc[d];
            if (HASBIAS) r += bias[dd];
            if (GELU_OUT) r = 0.5f * r * (1.f + erff(r * 0.70710678118654752f));
            if (ADDXN)   r += xn[obase + (size_t)dd * NHW];
            out[obase + (size_t)dd * NHW] = r;
        }
    }
}

// ---------------------------------------------------------------------------
// LayerNorm over concat(x_1,x_2) channel dim (128) + fc5 (128->64) + bias + xn
// Chunked: 4 x 16 outputs/thread; weights staged per-chunk (8 KB LDS).
__global__ void k_ln_fc5(const float* __restrict__ x1p, const float* __restrict__ x2p,
                         const float* __restrict__ ln_g, const float* __restrict__ ln_b,
                         const float* __restrict__ w5, const float* __restrict__ b5,
                         const float* __restrict__ xn, float* __restrict__ out) {
    __shared__ float wl[128 * 16];     // one 16-wide output chunk of fc5
    __shared__ float gl[128], bl[128];
    int tid = threadIdx.x;
    if (tid < 128) { gl[tid] = ln_g[tid]; bl[tid] = ln_b[tid]; }

    int p  = blockIdx.x * 256 + tid;
    int b  = p >> 14;
    int hw = p & (NHW - 1);
    const float* a1 = x1p + (size_t)b * CHW + hw;
    const float* a2 = x2p + (size_t)b * CHW + hw;

    float s = 0.f, sq = 0.f;
    for (int c = 0; c < 64; ++c) { float v = a1[(size_t)c * NHW]; s += v; sq += v * v; }
    for (int c = 0; c < 64; ++c) { float v = a2[(size_t)c * NHW]; s += v; sq += v * v; }
    float m    = s * (1.f / 128.f);
    float var  = sq * (1.f / 128.f) - m * m;
    float rstd = rsqrtf(var + EPS);

    size_t obase = (size_t)b * CHW + hw;

    #pragma unroll 1
    for (int chunk = 0; chunk < 4; ++chunk) {
        __syncthreads();
        // stage w5[:, chunk*16 : chunk*16+16] -> wl[c][d16]
        #pragma unroll
        for (int k = 0; k < 8; ++k) {
            int idx = tid + (k << 8);        // 0..2047
            int c = idx >> 4, d = idx & 15;
            wl[idx] = w5[c * 64 + chunk * 16 + d];
        }
        __syncthreads();

        float acc[16];
        #pragma unroll
        for (int d = 0; d < 16; ++d) acc[d] = 0.f;

        for (int c = 0; c < 64; ++c) {
            float vn = (a1[(size_t)c * NHW] - m) * rstd * gl[c] + bl[c];
            const float* wrow = &wl[c * 16];
            #pragma unroll
            for (int d = 0; d < 16; ++d) acc[d] += vn * wrow[d];
        }
        for (int c = 0; c < 64; ++c) {
            float vn = (a2[(size_t)c * NHW] - m) * rstd * gl[64 + c] + bl[64 + c];
            const float* wrow = &wl[(64 + c) * 16];
            #pragma unroll
            for (int d = 0; d < 16; ++d) acc[d] += vn * wrow[d];
        }

        #pragma unroll
        for (int d = 0; d < 16; ++d) {
            int dd = chunk * 16 + d;
            out[obase + (size_t)dd * NHW] = acc[d] + b5[dd] + xn[obase + (size_t)dd * NHW];
        }
    }
}

// ---------------------------------------------------------------------------
// Depthwise 3x3 conv, dilation DIL, zero pad = DIL.
// BNIN: apply per-channel BN affine + relu to the loaded input values.
template<int DIL, bool HASBIAS, bool BNIN>
__global__ void k_dwconv(const float* __restrict__ in, const float* __restrict__ wgt,
                         const float* __restrict__ bias,
                         const float* __restrict__ meanc, const float* __restrict__ rstdc,
                         const float* __restrict__ bng, const float* __restrict__ bnb,
                         float* __restrict__ out) {
    int p = blockIdx.x * 256 + threadIdx.x;   // over SZ
    int w = p & 127, h = (p >> 7) & 127, c = (p >> 14) & 63;
    const float* ib = in + (size_t)(p >> 14) * NHW;   // (b*C+c) plane
    const float* wc = wgt + c * 9;
    float scale = 0.f, shift = 0.f;
    if (BNIN) {
        scale = rstdc[c] * bng[c];
        shift = bnb[c] - meanc[c] * scale;
    }
    float acc = HASBIAS ? bias[c] : 0.f;
    #pragma unroll
    for (int i = 0; i < 3; ++i) {
        int hh = h + (i - 1) * DIL;
        if (hh < 0 || hh >= NH) continue;
        #pragma unroll
        for (int j = 0; j < 3; ++j) {
            int ww = w + (j - 1) * DIL;
            if (ww < 0 || ww >= NW) continue;
            float v = ib[hh * NW + ww];
            if (BNIN) v = fmaxf(v * scale + shift, 0.f);
            acc += v * wc[i * 3 + j];
        }
    }
    out[p] = acc;
}

// ---------------------------------------------------------------------------
// Per-(b,c) plane sum and sumsq (for BN training-mode stats), block per plane
__global__ void k_plane_stats(const float* __restrict__ in,
                              float* __restrict__ psum, float* __restrict__ psq) {
    __shared__ float ss[256], sq[256];
    int bc = blockIdx.x, tid = threadIdx.x;
    const float* pl = in + (size_t)bc * NHW;
    float s = 0.f, q = 0.f;
    for (int i = tid; i < NHW; i += 256) { float v = pl[i]; s += v; q += v * v; }
    ss[tid] = s; sq[tid] = q; __syncthreads();
    for (int o = 128; o > 0; o >>= 1) {
        if (tid < o) { ss[tid] += ss[tid + o]; sq[tid] += sq[tid + o]; }
        __syncthreads();
    }
    if (tid == 0) { psum[bc] = ss[0]; psq[bc] = sq[0]; }
}

__global__ void k_bn_finalize(const float* __restrict__ psum, const float* __restrict__ psq,
                              float* __restrict__ meanc, float* __restrict__ rstdc) {
    int c = threadIdx.x;  // 64 threads
    float s = 0.f, q = 0.f;
    for (int b = 0; b < NB; ++b) { s += psum[b * 64 + c]; q += psq[b * 64 + c]; }
    const float inv = 1.f / (float)(NB * NHW);
    float m = s * inv;
    float v = q * inv - m * m;
    meanc[c] = m;
    rstdc[c] = rsqrtf(v + EPS);
}

// ---------------------------------------------------------------------------
// SE: s[b,c] = mean_{hw} 4*x2*y3 ; block per (b,c)
__global__ void k_se_reduce(const float* __restrict__ x2, const float* __restrict__ y3,
                            float* __restrict__ s) {
    __shared__ float ss[256];
    int bc = blockIdx.x, tid = threadIdx.x;
    const float* a  = x2 + (size_t)bc * NHW;
    const float* b_ = y3 + (size_t)bc * NHW;
    float acc = 0.f;
    for (int i = tid; i < NHW; i += 256) acc += a[i] * b_[i];
    ss[tid] = acc; __syncthreads();
    for (int o = 128; o > 0; o >>= 1) {
        if (tid < o) ss[tid] += ss[tid + o];
        __syncthreads();
    }
    if (tid == 0) s[bc] = ss[0] * (4.f / (float)NHW);
}

// e[b,c] = sigmoid(W2 @ relu(W1 @ s + b1) + b2) ; one block (64 threads) per b
__global__ void k_se_mlp(const float* __restrict__ s, const float* __restrict__ w1,
                         const float* __restrict__ b1, const float* __restrict__ w2,
                         const float* __restrict__ b2, float* __restrict__ e) {
    __shared__ float sh[64], e1[8];
    int b = blockIdx.x, tid = threadIdx.x;
    sh[tid] = s[b * 64 + tid];
    __syncthreads();
    if (tid < 8) {
        float a = b1[tid];
        for (int c = 0; c < 64; ++c) a += sh[c] * w1[tid * 64 + c];
        e1[tid] = a > 0.f ? a : 0.f;
    }
    __syncthreads();
    float a = b2[tid];
    #pragma unroll
    for (int j = 0; j < 8; ++j) a += e1[j] * w2[tid * 8 + j];
    e[b * 64 + tid] = 1.f / (1.f + expf(-a));
}

// out = x7 * (1 + e), x7 = 4*x2*y3
__global__ void k_final(const float* __restrict__ x2, const float* __restrict__ y3,
                        const float* __restrict__ e, float* __restrict__ out) {
    int p = blockIdx.x * 256 + threadIdx.x;
    int b = p >> 20, c = (p >> 14) & 63;
    out[p] = 4.f * x2[p] * y3[p] * (1.f + e[b * 64 + c]);
}

// ---------------------------------------------------------------------------
extern "C" void kernel_launch(void* const* d_in, const int* in_sizes, int n_in,
                              void* d_out, int out_size, void* d_ws, size_t ws_size,
                              hipStream_t stream) {
    const float* x     = (const float*)d_in[0];
    const float* fc1w  = (const float*)d_in[1];
    const float* fc1b  = (const float*)d_in[2];
    const float* fc2w  = (const float*)d_in[3];
    const float* fc2b  = (const float*)d_in[4];
    const float* fc3w  = (const float*)d_in[5];
    const float* fc3b  = (const float*)d_in[6];
    const float* fc4w  = (const float*)d_in[7];
    const float* fc4b  = (const float*)d_in[8];
    const float* fc5w  = (const float*)d_in[9];
    const float* fc5b  = (const float*)d_in[10];
    const float* lng   = (const float*)d_in[11];
    const float* lnb   = (const float*)d_in[12];
    const float* pcw   = (const float*)d_in[13];
    const float* dww   = (const float*)d_in[14];
    const float* dwb   = (const float*)d_in[15];
    const float* dwbng = (const float*)d_in[16];
    const float* dwbnb = (const float*)d_in[17];
    const float* ddw   = (const float*)d_in[18];
    const float* ddbng = (const float*)d_in[19];
    const float* ddbnb = (const float*)d_in[20];
    const float* sew1  = (const float*)d_in[21];
    const float* seb1  = (const float*)d_in[22];
    const float* sew2  = (const float*)d_in[23];
    const float* seb2  = (const float*)d_in[24];

    float* out  = (float*)d_out;
    float* ws   = (float*)d_ws;
    float* buf0 = ws;                      // xn, later x2
    float* buf1 = ws + (size_t)SZ;         // t1, x_2, d1, y3
    float* buf2 = ws + (size_t)2 * SZ;     // t2, x1, d2
    float* st   = ws + (size_t)3 * SZ;
    float* psum   = st;          // 512
    float* psq    = st + 512;    // 512
    float* meanc1 = st + 1024;   // 64
    float* rstdc1 = st + 1088;   // 64
    float* meanc2 = st + 1152;   // 64
    float* rstdc2 = st + 1216;   // 64
    float* svec   = st + 1280;   // 512
    float* evec   = st + 1792;   // 512

    dim3 blk(256);
    const float* nil = nullptr;

    // xn = transpose(x)
    k_transpose<<<NB * (NHW / 64), blk, 0, stream>>>(x, buf0);
    // t1 = gelu(fc1(roll_h(xn,+1)))
    k_fc<0, true,  false, false, true, false><<<NPOS / 256, blk, 0, stream>>>(buf0, fc1w, fc1b, nil, nil, nil, nil, nil, buf1);
    // t2 = gelu(fc3(roll_w(xn,-1)))
    k_fc<2, true,  false, false, true, false><<<NPOS / 256, blk, 0, stream>>>(buf0, fc3w, fc3b, nil, nil, nil, nil, nil, buf2);
    // x_1 = fc2(roll_w(t1,+1)) + xn   (d_out used as scratch, fully rewritten later)
    k_fc<1, false, true,  false, true, false><<<NPOS / 256, blk, 0, stream>>>(buf1, fc2w, fc2b, buf0, nil, nil, nil, nil, out);
    // x_2 = fc4(roll_h(t2,+1)) + xn
    k_fc<0, false, true,  false, true, false><<<NPOS / 256, blk, 0, stream>>>(buf2, fc4w, fc4b, buf0, nil, nil, nil, nil, buf1);
    // x1 = LN(concat(x_1,x_2)) @ fc5 + b5 + xn
    k_ln_fc5<<<NPOS / 256, blk, 0, stream>>>(out, buf1, lng, lnb, fc5w, fc5b, buf0, buf2);
    // x2 = pc(x1)
    k_fc<3, false, false, true, false, false><<<NPOS / 256, blk, 0, stream>>>(buf2, pcw, nil, nil, nil, nil, nil, nil, buf0);
    // d1 = dwconv3x3(x2, dil=1) + dw_b
    k_dwconv<1, true, false><<<SZ / 256, blk, 0, stream>>>(buf0, dww, dwb, nil, nil, nil, nil, buf1);
    k_plane_stats<<<NB * NC, blk, 0, stream>>>(buf1, psum, psq);
    k_bn_finalize<<<1, 64, 0, stream>>>(psum, psq, meanc1, rstdc1);
    // d2 = dwconv3x3(relu(bn1(d1)), dil=2)   [BN+relu fused into load]
    k_dwconv<2, false, true><<<SZ / 256, blk, 0, stream>>>(buf1, ddw, nil, meanc1, rstdc1, dwbng, dwbnb, buf2);
    k_plane_stats<<<NB * NC, blk, 0, stream>>>(buf2, psum, psq);
    k_bn_finalize<<<1, 64, 0, stream>>>(psum, psq, meanc2, rstdc2);
    // y3 = pc(relu(bn2(d2)))                 [BN+relu fused into load]
    k_fc<3, false, false, true, false, true><<<NPOS / 256, blk, 0, stream>>>(buf2, pcw, nil, nil, meanc2, rstdc2, ddbng, ddbnb, buf1);
    // SE + final: out = 4*x2*y3*(1+e)
    k_se_reduce<<<NB * NC, blk, 0, stream>>>(buf0, buf1, svec);
    k_se_mlp<<<NB, 64, 0, stream>>>(svec, sew1, seb1, sew2, seb2, evec);
    k_final<<<SZ / 256, blk, 0, stream>>>(buf0, buf1, evec, out);
}

// Round 3
// 401.278 us; speedup vs baseline: 1.3136x; 1.2762x over previous
//
#include <hip/hip_runtime.h>

// Problem constants (fixed by the reference)
constexpr int NB  = 8;
constexpr int NC  = 64;
constexpr int NH  = 128;
constexpr int NW  = 128;
constexpr int NHW = NH * NW;          // 16384
constexpr int CHW = NC * NHW;         // 1048576
constexpr int SZ  = NB * CHW;         // 8388608 elements per tensor
constexpr int NPOS = NB * NHW;        // 131072 spatial positions
constexpr float EPS = 1e-5f;

// ---------------------------------------------------------------------------
// (B,N,C) -> (B,C,H,W) transpose, LDS-tiled, coalesced both sides
__global__ void k_transpose(const float* __restrict__ x, float* __restrict__ xn) {
    __shared__ float t[64 * 65];
    int b   = blockIdx.x >> 8;            // 256 tiles of 64 positions per b
    int hw0 = (blockIdx.x & 255) << 6;
    int tid = threadIdx.x;
    #pragma unroll
    for (int k = 0; k < 16; ++k) {
        int idx = tid + (k << 8);
        int c = idx & 63, hwl = idx >> 6;
        t[c * 65 + hwl] = x[((size_t)b * NHW + hw0 + hwl) * NC + c];
    }
    __syncthreads();
    #pragma unroll
    for (int k = 0; k < 16; ++k) {
        int idx = tid + (k << 8);
        int hwl = idx & 63, c = idx >> 6;
        xn[(size_t)(b * NC + c) * NHW + hw0 + hwl] = t[c * 65 + hwl];
    }
}

// ---------------------------------------------------------------------------
// Rolled channel-linear. Block = 64 positions x 4 waves; wave g computes output
// channels [16g, 16g+16). Grid = NPOS/64 = 2048 blocks. The 4 waves issue
// identical input loads (L1-served after the first wave).
// MODE 0: rollH (h-c)%H | 1: rollW (w-c)%W | 2: rollW (w+c)%W | 3: no roll
// WTRANS: weight indexed [d][c] (pc_w) instead of [c][d] (fc*)
// BNRELU_IN: apply per-channel affine (BN) + relu to loaded input values
template<int MODE, bool GELU_OUT, bool ADDXN, bool WTRANS, bool HASBIAS, bool BNRELU_IN>
__global__ void k_fc(const float* __restrict__ in, const float* __restrict__ wgt,
                     const float* __restrict__ bias, const float* __restrict__ xn,
                     const float* __restrict__ meanc, const float* __restrict__ rstdc,
                     const float* __restrict__ bng, const float* __restrict__ bnb,
                     float* __restrict__ out) {
    __shared__ float wl[64 * 65];       // stride 65 only used when WTRANS
    __shared__ float scl[64], sft[64];
    int tid = threadIdx.x;
    if (WTRANS) {
        #pragma unroll
        for (int k = 0; k < 16; ++k) {
            int idx = tid + (k << 8);
            int o = idx >> 6, cc = idx & 63;
            wl[cc * 65 + o] = wgt[idx];   // store transposed, padded
        }
    } else {
        #pragma unroll
        for (int k = 0; k < 16; ++k) {
            int idx = tid + (k << 8);
            wl[idx] = wgt[idx];
        }
    }
    if (BNRELU_IN && tid < 64) {
        float s = rstdc[tid] * bng[tid];
        scl[tid] = s;
        sft[tid] = bnb[tid] - meanc[tid] * s;
    }
    __syncthreads();

    int posl = tid & 63;
    int grp  = tid >> 6;                  // wave index = output channel group
    int p  = blockIdx.x * 64 + posl;      // 0 .. NPOS-1
    int b  = p >> 14;
    int hw = p & (NHW - 1);
    int h  = hw >> 7, w = hw & 127;

    const float* inb = in + (size_t)b * CHW;
    size_t obase = (size_t)b * CHW + hw;
    constexpr int LDW = WTRANS ? 65 : 64;

    float acc[16];
    #pragma unroll
    for (int d = 0; d < 16; ++d) acc[d] = 0.f;

    for (int c = 0; c < 64; ++c) {
        int addr;
        if (MODE == 0)      addr = c * NHW + (((h - c) & 127) << 7) + w;
        else if (MODE == 1) addr = c * NHW + (h << 7) + ((w - c) & 127);
        else if (MODE == 2) addr = c * NHW + (h << 7) + ((w + c) & 127);
        else                addr = c * NHW + hw;
        float v = inb[addr];
        if (BNRELU_IN) { v = fmaxf(v * scl[c] + sft[c], 0.f); }
        const float* wrow = &wl[c * LDW + grp * 16];
        #pragma unroll
        for (int d = 0; d < 16; ++d)
            acc[d] += v * wrow[d];
    }

    #pragma unroll
    for (int d = 0; d < 16; ++d) {
        int dd = grp * 16 + d;
        float r = acc[d];
        if (HASBIAS) r += bias[dd];
        if (GELU_OUT) r = 0.5f * r * (1.f + erff(r * 0.70710678118654752f));
        if (ADDXN)   r += xn[obase + (size_t)dd * NHW];
        out[obase + (size_t)dd * NHW] = r;
    }
}

// ---------------------------------------------------------------------------
// LayerNorm over concat(x_1,x_2) channel dim (128) + fc5 (128->64) + bias + xn
// Block = 64 positions x 4 waves; wave g computes output channels [16g,16g+16).
// LN stats computed redundantly per wave (loads L1-served).
__global__ void k_ln_fc5(const float* __restrict__ x1p, const float* __restrict__ x2p,
                         const float* __restrict__ ln_g, const float* __restrict__ ln_b,
                         const float* __restrict__ w5, const float* __restrict__ b5,
                         const float* __restrict__ xn, float* __restrict__ out) {
    __shared__ float wl[128 * 64];     // full fc5 weight, 32 KB
    __shared__ float gl[128], bl[128];
    int tid = threadIdx.x;
    #pragma unroll
    for (int k = 0; k < 32; ++k) wl[tid + (k << 8)] = w5[tid + (k << 8)];
    if (tid < 128) { gl[tid] = ln_g[tid]; bl[tid] = ln_b[tid]; }
    __syncthreads();

    int posl = tid & 63;
    int grp  = tid >> 6;
    int p  = blockIdx.x * 64 + posl;
    int b  = p >> 14;
    int hw = p & (NHW - 1);
    const float* a1 = x1p + (size_t)b * CHW + hw;
    const float* a2 = x2p + (size_t)b * CHW + hw;

    float s = 0.f, sq = 0.f;
    for (int c = 0; c < 64; ++c) { float v = a1[(size_t)c * NHW]; s += v; sq += v * v; }
    for (int c = 0; c < 64; ++c) { float v = a2[(size_t)c * NHW]; s += v; sq += v * v; }
    float m    = s * (1.f / 128.f);
    float var  = sq * (1.f / 128.f) - m * m;
    float rstd = rsqrtf(var + EPS);

    float acc[16];
    #pragma unroll
    for (int d = 0; d < 16; ++d) acc[d] = 0.f;

    for (int c = 0; c < 64; ++c) {
        float vn = (a1[(size_t)c * NHW] - m) * rstd * gl[c] + bl[c];
        const float* wrow = &wl[c * 64 + grp * 16];
        #pragma unroll
        for (int d = 0; d < 16; ++d) acc[d] += vn * wrow[d];
    }
    for (int c = 0; c < 64; ++c) {
        float vn = (a2[(size_t)c * NHW] - m) * rstd * gl[64 + c] + bl[64 + c];
        const float* wrow = &wl[(64 + c) * 64 + grp * 16];
        #pragma unroll
        for (int d = 0; d < 16; ++d) acc[d] += vn * wrow[d];
    }

    size_t obase = (size_t)b * CHW + hw;
    #pragma unroll
    for (int d = 0; d < 16; ++d) {
        int dd = grp * 16 + d;
        out[obase + (size_t)dd * NHW] = acc[d] + b5[dd] + xn[obase + (size_t)dd * NHW];
    }
}

// ---------------------------------------------------------------------------
// Depthwise 3x3 conv, dilation DIL, zero pad = DIL.
// BNIN: apply per-channel BN affine + relu to the loaded input values.
template<int DIL, bool HASBIAS, bool BNIN>
__global__ void k_dwconv(const float* __restrict__ in, const float* __restrict__ wgt,
                         const float* __restrict__ bias,
                         const float* __restrict__ meanc, const float* __restrict__ rstdc,
                         const float* __restrict__ bng, const float* __restrict__ bnb,
                         float* __restrict__ out) {
    int p = blockIdx.x * 256 + threadIdx.x;   // over SZ
    int w = p & 127, h = (p >> 7) & 127, c = (p >> 14) & 63;
    const float* ib = in + (size_t)(p >> 14) * NHW;   // (b*C+c) plane
    const float* wc = wgt + c * 9;
    float scale = 0.f, shift = 0.f;
    if (BNIN) {
        scale = rstdc[c] * bng[c];
        shift = bnb[c] - meanc[c] * scale;
    }
    float acc = HASBIAS ? bias[c] : 0.f;
    #pragma unroll
    for (int i = 0; i < 3; ++i) {
        int hh = h + (i - 1) * DIL;
        if (hh < 0 || hh >= NH) continue;
        #pragma unroll
        for (int j = 0; j < 3; ++j) {
            int ww = w + (j - 1) * DIL;
            if (ww < 0 || ww >= NW) continue;
            float v = ib[hh * NW + ww];
            if (BNIN) v = fmaxf(v * scale + shift, 0.f);
            acc += v * wc[i * 3 + j];
        }
    }
    out[p] = acc;
}

// ---------------------------------------------------------------------------
// Per-(b,c) plane sum/sumsq, split 4 ways per plane (grid = 512*4 = 2048)
__global__ void k_plane_stats(const float* __restrict__ in,
                              float* __restrict__ psum, float* __restrict__ psq) {
    __shared__ float ss[256], sq[256];
    int q   = blockIdx.x & 3;
    int bc  = blockIdx.x >> 2;
    int tid = threadIdx.x;
    const float* pl = in + (size_t)bc * NHW + q * (NHW / 4);
    float s = 0.f, qq = 0.f;
    for (int i = tid; i < NHW / 4; i += 256) { float v = pl[i]; s += v; qq += v * v; }
    ss[tid] = s; sq[tid] = qq; __syncthreads();
    for (int o = 128; o > 0; o >>= 1) {
        if (tid < o) { ss[tid] += ss[tid + o]; sq[tid] += sq[tid + o]; }
        __syncthreads();
    }
    if (tid == 0) { psum[blockIdx.x] = ss[0]; psq[blockIdx.x] = sq[0]; }
}

__global__ void k_bn_finalize(const float* __restrict__ psum, const float* __restrict__ psq,
                              float* __restrict__ meanc, float* __restrict__ rstdc) {
    int c = threadIdx.x;  // 64 threads
    float s = 0.f, q = 0.f;
    for (int b = 0; b < NB; ++b)
        for (int j = 0; j < 4; ++j) {
            s += psum[(b * 64 + c) * 4 + j];
            q += psq[(b * 64 + c) * 4 + j];
        }
    const float inv = 1.f / (float)(NB * NHW);
    float m = s * inv;
    float v = q * inv - m * m;
    meanc[c] = m;
    rstdc[c] = rsqrtf(v + EPS);
}

// ---------------------------------------------------------------------------
// SE partial: s4[bc*4+q] = sum_{quarter} x2*y3 ; grid = 2048
__global__ void k_se_reduce(const float* __restrict__ x2, const float* __restrict__ y3,
                            float* __restrict__ s4) {
    __shared__ float ss[256];
    int q   = blockIdx.x & 3;
    int bc  = blockIdx.x >> 2;
    int tid = threadIdx.x;
    const float* a  = x2 + (size_t)bc * NHW + q * (NHW / 4);
    const float* b_ = y3 + (size_t)bc * NHW + q * (NHW / 4);
    float acc = 0.f;
    for (int i = tid; i < NHW / 4; i += 256) acc += a[i] * b_[i];
    ss[tid] = acc; __syncthreads();
    for (int o = 128; o > 0; o >>= 1) {
        if (tid < o) ss[tid] += ss[tid + o];
        __syncthreads();
    }
    if (tid == 0) s4[blockIdx.x] = ss[0];
}

// e[b,c] = sigmoid(W2 @ relu(W1 @ s + b1) + b2) ; one block (64 threads) per b
__global__ void k_se_mlp(const float* __restrict__ s4, const float* __restrict__ w1,
                         const float* __restrict__ b1, const float* __restrict__ w2,
                         const float* __restrict__ b2, float* __restrict__ e) {
    __shared__ float sh[64], e1[8];
    int b = blockIdx.x, tid = threadIdx.x;
    float sv = 0.f;
    #pragma unroll
    for (int j = 0; j < 4; ++j) sv += s4[(b * 64 + tid) * 4 + j];
    sh[tid] = sv * (4.f / (float)NHW);
    __syncthreads();
    if (tid < 8) {
        float a = b1[tid];
        for (int c = 0; c < 64; ++c) a += sh[c] * w1[tid * 64 + c];
        e1[tid] = a > 0.f ? a : 0.f;
    }
    __syncthreads();
    float a = b2[tid];
    #pragma unroll
    for (int j = 0; j < 8; ++j) a += e1[j] * w2[tid * 8 + j];
    e[b * 64 + tid] = 1.f / (1.f + expf(-a));
}

// out = x7 * (1 + e), x7 = 4*x2*y3
__global__ void k_final(const float* __restrict__ x2, const float* __restrict__ y3,
                        const float* __restrict__ e, float* __restrict__ out) {
    int p = blockIdx.x * 256 + threadIdx.x;
    int b = p >> 20, c = (p >> 14) & 63;
    out[p] = 4.f * x2[p] * y3[p] * (1.f + e[b * 64 + c]);
}

// ---------------------------------------------------------------------------
extern "C" void kernel_launch(void* const* d_in, const int* in_sizes, int n_in,
                              void* d_out, int out_size, void* d_ws, size_t ws_size,
                              hipStream_t stream) {
    const float* x     = (const float*)d_in[0];
    const float* fc1w  = (const float*)d_in[1];
    const float* fc1b  = (const float*)d_in[2];
    const float* fc2w  = (const float*)d_in[3];
    const float* fc2b  = (const float*)d_in[4];
    const float* fc3w  = (const float*)d_in[5];
    const float* fc3b  = (const float*)d_in[6];
    const float* fc4w  = (const float*)d_in[7];
    const float* fc4b  = (const float*)d_in[8];
    const float* fc5w  = (const float*)d_in[9];
    const float* fc5b  = (const float*)d_in[10];
    const float* lng   = (const float*)d_in[11];
    const float* lnb   = (const float*)d_in[12];
    const float* pcw   = (const float*)d_in[13];
    const float* dww   = (const float*)d_in[14];
    const float* dwb   = (const float*)d_in[15];
    const float* dwbng = (const float*)d_in[16];
    const float* dwbnb = (const float*)d_in[17];
    const float* ddw   = (const float*)d_in[18];
    const float* ddbng = (const float*)d_in[19];
    const float* ddbnb = (const float*)d_in[20];
    const float* sew1  = (const float*)d_in[21];
    const float* seb1  = (const float*)d_in[22];
    const float* sew2  = (const float*)d_in[23];
    const float* seb2  = (const float*)d_in[24];

    float* out  = (float*)d_out;
    float* ws   = (float*)d_ws;
    float* buf0 = ws;                      // xn, later x2
    float* buf1 = ws + (size_t)SZ;         // t1, x_2, d1, y3
    float* buf2 = ws + (size_t)2 * SZ;     // t2, x1, d2
    float* st   = ws + (size_t)3 * SZ;
    float* psum   = st;          // 2048
    float* psq    = st + 2048;   // 2048
    float* meanc1 = st + 4096;   // 64
    float* rstdc1 = st + 4160;   // 64
    float* meanc2 = st + 4224;   // 64
    float* rstdc2 = st + 4288;   // 64
    float* svec   = st + 4352;   // 2048
    float* evec   = st + 6400;   // 512

    dim3 blk(256);
    const float* nil = nullptr;

    // xn = transpose(x)
    k_transpose<<<NB * (NHW / 64), blk, 0, stream>>>(x, buf0);
    // t1 = gelu(fc1(roll_h(xn,+1)))
    k_fc<0, true,  false, false, true, false><<<NPOS / 64, blk, 0, stream>>>(buf0, fc1w, fc1b, nil, nil, nil, nil, nil, buf1);
    // t2 = gelu(fc3(roll_w(xn,-1)))
    k_fc<2, true,  false, false, true, false><<<NPOS / 64, blk, 0, stream>>>(buf0, fc3w, fc3b, nil, nil, nil, nil, nil, buf2);
    // x_1 = fc2(roll_w(t1,+1)) + xn   (d_out used as scratch, fully rewritten later)
    k_fc<1, false, true,  false, true, false><<<NPOS / 64, blk, 0, stream>>>(buf1, fc2w, fc2b, buf0, nil, nil, nil, nil, out);
    // x_2 = fc4(roll_h(t2,+1)) + xn
    k_fc<0, false, true,  false, true, false><<<NPOS / 64, blk, 0, stream>>>(buf2, fc4w, fc4b, buf0, nil, nil, nil, nil, buf1);
    // x1 = LN(concat(x_1,x_2)) @ fc5 + b5 + xn
    k_ln_fc5<<<NPOS / 64, blk, 0, stream>>>(out, buf1, lng, lnb, fc5w, fc5b, buf0, buf2);
    // x2 = pc(x1)
    k_fc<3, false, false, true, false, false><<<NPOS / 64, blk, 0, stream>>>(buf2, pcw, nil, nil, nil, nil, nil, nil, buf0);
    // d1 = dwconv3x3(x2, dil=1) + dw_b
    k_dwconv<1, true, false><<<SZ / 256, blk, 0, stream>>>(buf0, dww, dwb, nil, nil, nil, nil, buf1);
    k_plane_stats<<<NB * NC * 4, blk, 0, stream>>>(buf1, psum, psq);
    k_bn_finalize<<<1, 64, 0, stream>>>(psum, psq, meanc1, rstdc1);
    // d2 = dwconv3x3(relu(bn1(d1)), dil=2)   [BN+relu fused into load]
    k_dwconv<2, false, true><<<SZ / 256, blk, 0, stream>>>(buf1, ddw, nil, meanc1, rstdc1, dwbng, dwbnb, buf2);
    k_plane_stats<<<NB * NC * 4, blk, 0, stream>>>(buf2, psum, psq);
    k_bn_finalize<<<1, 64, 0, stream>>>(psum, psq, meanc2, rstdc2);
    // y3 = pc(relu(bn2(d2)))                 [BN+relu fused into load]
    k_fc<3, false, false, true, false, true><<<NPOS / 64, blk, 0, stream>>>(buf2, pcw, nil, nil, meanc2, rstdc2, ddbng, ddbnb, buf1);
    // SE + final: out = 4*x2*y3*(1+e)
    k_se_reduce<<<NB * NC * 4, blk, 0, stream>>>(buf0, buf1, svec);
    k_se_mlp<<<NB, 64, 0, stream>>>(svec, sew1, seb1, sew2, seb2, evec);
    k_final<<<SZ / 256, blk, 0, stream>>>(buf0, buf1, evec, out);
}

// Round 4
// 279.935 us; speedup vs baseline: 1.8829x; 1.4335x over previous
//
#include <hip/hip_runtime.h>

// Problem constants (fixed by the reference)
constexpr int NB  = 8;
constexpr int NC  = 64;
constexpr int NH  = 128;
constexpr int NW  = 128;
constexpr int NHW = NH * NW;          // 16384
constexpr int CHW = NC * NHW;         // 1048576
constexpr int SZ  = NB * CHW;         // 8388608 elements per tensor
constexpr int NPOS = NB * NHW;        // 131072 spatial positions
constexpr float EPS = 1e-5f;

using bf8   = __attribute__((ext_vector_type(8))) short;   // 8 bf16 = 4 VGPR
using f32x4 = __attribute__((ext_vector_type(4))) float;

static __device__ inline short f2bf(float f) {
    union { float f; unsigned int u; } v; v.f = f;
    unsigned int r = v.u + 0x7fffu + ((v.u >> 16) & 1u);   // RNE
    return (short)(r >> 16);
}

// ---------------------------------------------------------------------------
// (B,N,C) -> (B,C,H,W) transpose, LDS-tiled, coalesced both sides
__global__ void k_transpose(const float* __restrict__ x, float* __restrict__ xn) {
    __shared__ float t[64 * 65];
    int b   = blockIdx.x >> 8;
    int hw0 = (blockIdx.x & 255) << 6;
    int tid = threadIdx.x;
    #pragma unroll
    for (int k = 0; k < 16; ++k) {
        int idx = tid + (k << 8);
        int c = idx & 63, hwl = idx >> 6;
        t[c * 65 + hwl] = x[((size_t)b * NHW + hw0 + hwl) * NC + c];
    }
    __syncthreads();
    #pragma unroll
    for (int k = 0; k < 16; ++k) {
        int idx = tid + (k << 8);
        int hwl = idx & 63, c = idx >> 6;
        xn[(size_t)(b * NC + c) * NHW + hw0 + hwl] = t[c * 65 + hwl];
    }
}

// ---------------------------------------------------------------------------
// MFMA channel-linear (K=64). A = weights (rows d, staged LDS bf16 swizzled),
// B = input (cols = 16 positions/wave), D[d][pos]. Block = 4 waves = 64 pos.
// MODE 0: rollH (h-c)%H | 1: rollW (w-c)%W | 2: rollW (w+c)%W | 3: no roll
// WTRANS: weight in global is [d][c] (pc_w); else [c][d] (fc*)
template<int MODE, bool GELU_OUT, bool ADDXN, bool WTRANS, bool HASBIAS, bool BNRELU_IN>
__global__ __launch_bounds__(256) void
k_mfc(const float* __restrict__ in, const float* __restrict__ wgt,
      const float* __restrict__ bias, const float* __restrict__ xn,
      const float* __restrict__ meanc, const float* __restrict__ rstdc,
      const float* __restrict__ bng, const float* __restrict__ bnb,
      float* __restrict__ out) {
    __shared__ short wt[64 * 64];        // WT[d][c] bf16, swizzled c ^ ((d&7)<<3)
    __shared__ float scl[64], sft[64];
    int tid = threadIdx.x;
    int l = tid & 63, wv = tid >> 6;

    if (!WTRANS) {
        // wgt[c][d]: lanes read consecutive d (coalesced); write c-pairs packed
        #pragma unroll
        for (int i = 0; i < 8; ++i) {
            int c0 = wv * 2 + i * 8;
            float v0 = wgt[c0 * 64 + l];
            float v1 = wgt[(c0 + 1) * 64 + l];
            unsigned int pk = (unsigned int)(unsigned short)f2bf(v0) |
                              ((unsigned int)(unsigned short)f2bf(v1) << 16);
            *(unsigned int*)&wt[l * 64 + (c0 ^ ((l & 7) << 3))] = pk;
        }
    } else {
        // wgt[d][c]: lanes read consecutive c (coalesced); row d fixed per iter
        #pragma unroll
        for (int i = 0; i < 16; ++i) {
            int d = wv * 16 + i;
            wt[d * 64 + (l ^ ((d & 7) << 3))] = f2bf(wgt[d * 64 + l]);
        }
    }
    if (BNRELU_IN && tid < 64) {
        float s = rstdc[tid] * bng[tid];
        scl[tid] = s;
        sft[tid] = bnb[tid] - meanc[tid] * s;
    }
    __syncthreads();

    int q = l >> 4, col = l & 15;
    int p  = blockIdx.x * 64 + wv * 16 + col;
    int b  = p >> 14;
    int hw = p & (NHW - 1);
    int h  = hw >> 7, w = hw & 127;
    const float* inb = in + (size_t)b * CHW;

    f32x4 acc[4];
    #pragma unroll
    for (int dt = 0; dt < 4; ++dt) acc[dt] = (f32x4){0.f, 0.f, 0.f, 0.f};

    #pragma unroll
    for (int ks = 0; ks < 2; ++ks) {
        bf8 bfr;
        #pragma unroll
        for (int j = 0; j < 8; ++j) {
            int c = ks * 32 + q * 8 + j;
            int addr;
            if (MODE == 0)      addr = c * NHW + (((h - c) & 127) << 7) + w;
            else if (MODE == 1) addr = c * NHW + (h << 7) + ((w - c) & 127);
            else if (MODE == 2) addr = c * NHW + (h << 7) + ((w + c) & 127);
            else                addr = c * NHW + hw;
            float v = inb[addr];
            if (BNRELU_IN) v = fmaxf(v * scl[c] + sft[c], 0.f);
            bfr[j] = f2bf(v);
        }
        #pragma unroll
        for (int dt = 0; dt < 4; ++dt) {
            int d = dt * 16 + col;
            bf8 afr = *(bf8*)&wt[d * 64 + ((ks * 32 + q * 8) ^ ((d & 7) << 3))];
            acc[dt] = __builtin_amdgcn_mfma_f32_16x16x32_bf16(afr, bfr, acc[dt], 0, 0, 0);
        }
    }

    size_t obase = (size_t)b * CHW + hw;
    #pragma unroll
    for (int dt = 0; dt < 4; ++dt) {
        #pragma unroll
        for (int r = 0; r < 4; ++r) {
            int d = dt * 16 + q * 4 + r;
            float val = acc[dt][r];
            if (HASBIAS) val += bias[d];
            if (GELU_OUT) val = 0.5f * val * (1.f + erff(val * 0.70710678118654752f));
            size_t oa = obase + (size_t)d * NHW;
            if (ADDXN) val += xn[oa];
            out[oa] = val;
        }
    }
}

// ---------------------------------------------------------------------------
// Tiny: P[d] = sum_c g[c]*w5[c][d], Q[d] = sum_c b[c]*w5[c][d]
__global__ void k_pq(const float* __restrict__ w5, const float* __restrict__ lng,
                     const float* __restrict__ lnb, float* __restrict__ PQ) {
    int d = threadIdx.x;   // 64
    float P = 0.f, Q = 0.f;
    for (int c = 0; c < 128; ++c) {
        float wv = w5[c * 64 + d];
        P += lng[c] * wv;
        Q += lnb[c] * wv;
    }
    PQ[d] = P; PQ[64 + d] = Q;
}

// ---------------------------------------------------------------------------
// LN(concat(x_1,x_2)) @ fc5 + b5 + xn via MFMA, K=128, LN folded:
// out = rstd*(A@(g.*W)) + Q - m*rstd*P + b5 + xn. Stats via shfl_xor.
__global__ __launch_bounds__(256) void
k_mln(const float* __restrict__ x1p, const float* __restrict__ x2p,
      const float* __restrict__ w5, const float* __restrict__ lng,
      const float* __restrict__ PQ, const float* __restrict__ b5,
      const float* __restrict__ xn, float* __restrict__ out) {
    __shared__ short wt[64 * 128];       // WT[d][c'] = g[c']*w5[c'][d], swizzled
    int tid = threadIdx.x;
    int l = tid & 63, wv = tid >> 6;

    #pragma unroll
    for (int i = 0; i < 16; ++i) {
        int c0 = wv * 2 + i * 8;
        float v0 = lng[c0]     * w5[c0 * 64 + l];
        float v1 = lng[c0 + 1] * w5[(c0 + 1) * 64 + l];
        unsigned int pk = (unsigned int)(unsigned short)f2bf(v0) |
                          ((unsigned int)(unsigned short)f2bf(v1) << 16);
        *(unsigned int*)&wt[l * 128 + (c0 ^ ((l & 7) << 3))] = pk;
    }
    __syncthreads();

    int q = l >> 4, col = l & 15;
    int p  = blockIdx.x * 64 + wv * 16 + col;
    int b  = p >> 14;
    int hw = p & (NHW - 1);

    f32x4 acc[4];
    #pragma unroll
    for (int dt = 0; dt < 4; ++dt) acc[dt] = (f32x4){0.f, 0.f, 0.f, 0.f};

    float ss = 0.f, sq = 0.f;
    #pragma unroll
    for (int ks = 0; ks < 4; ++ks) {
        const float* src = (ks < 2) ? x1p : x2p;
        const float* sb  = src + (size_t)b * CHW + hw;
        bf8 bfr;
        #pragma unroll
        for (int j = 0; j < 8; ++j) {
            int c = (ks * 32 + q * 8 + j) & 63;
            float v = sb[(size_t)c * NHW];
            ss += v; sq += v * v;
            bfr[j] = f2bf(v);
        }
        #pragma unroll
        for (int dt = 0; dt < 4; ++dt) {
            int d = dt * 16 + col;
            bf8 afr = *(bf8*)&wt[d * 128 + ((ks * 32 + q * 8) ^ ((d & 7) << 3))];
            acc[dt] = __builtin_amdgcn_mfma_f32_16x16x32_bf16(afr, bfr, acc[dt], 0, 0, 0);
        }
    }
    // per-position stats: reduce over the 4 lane-quarters holding this col
    ss += __shfl_xor(ss, 16); ss += __shfl_xor(ss, 32);
    sq += __shfl_xor(sq, 16); sq += __shfl_xor(sq, 32);
    float m    = ss * (1.f / 128.f);
    float var  = sq * (1.f / 128.f) - m * m;
    float rstd = rsqrtf(var + EPS);
    float mr   = m * rstd;

    size_t obase = (size_t)b * CHW + hw;
    #pragma unroll
    for (int dt = 0; dt < 4; ++dt) {
        #pragma unroll
        for (int r = 0; r < 4; ++r) {
            int d = dt * 16 + q * 4 + r;
            float val = rstd * acc[dt][r] + PQ[64 + d] - mr * PQ[d] + b5[d];
            size_t oa = obase + (size_t)d * NHW;
            out[oa] = val + xn[oa];
        }
    }
}

// ---------------------------------------------------------------------------
// Depthwise 3x3 conv, dilation DIL, zero pad = DIL.
template<int DIL, bool HASBIAS, bool BNIN>
__global__ void k_dwconv(const float* __restrict__ in, const float* __restrict__ wgt,
                         const float* __restrict__ bias,
                         const float* __restrict__ meanc, const float* __restrict__ rstdc,
                         const float* __restrict__ bng, const float* __restrict__ bnb,
                         float* __restrict__ out) {
    int p = blockIdx.x * 256 + threadIdx.x;   // over SZ
    int w = p & 127, h = (p >> 7) & 127, c = (p >> 14) & 63;
    const float* ib = in + (size_t)(p >> 14) * NHW;
    const float* wc = wgt + c * 9;
    float scale = 0.f, shift = 0.f;
    if (BNIN) {
        scale = rstdc[c] * bng[c];
        shift = bnb[c] - meanc[c] * scale;
    }
    float acc = HASBIAS ? bias[c] : 0.f;
    #pragma unroll
    for (int i = 0; i < 3; ++i) {
        int hh = h + (i - 1) * DIL;
        if (hh < 0 || hh >= NH) continue;
        #pragma unroll
        for (int j = 0; j < 3; ++j) {
            int ww = w + (j - 1) * DIL;
            if (ww < 0 || ww >= NW) continue;
            float v = ib[hh * NW + ww];
            if (BNIN) v = fmaxf(v * scale + shift, 0.f);
            acc += v * wc[i * 3 + j];
        }
    }
    out[p] = acc;
}

// ---------------------------------------------------------------------------
// Per-(b,c) plane sum/sumsq, split 4 ways per plane (grid = 2048)
__global__ void k_plane_stats(const float* __restrict__ in,
                              float* __restrict__ psum, float* __restrict__ psq) {
    __shared__ float ss[256], sq[256];
    int q   = blockIdx.x & 3;
    int bc  = blockIdx.x >> 2;
    int tid = threadIdx.x;
    const float* pl = in + (size_t)bc * NHW + q * (NHW / 4);
    float s = 0.f, qq = 0.f;
    for (int i = tid; i < NHW / 4; i += 256) { float v = pl[i]; s += v; qq += v * v; }
    ss[tid] = s; sq[tid] = qq; __syncthreads();
    for (int o = 128; o > 0; o >>= 1) {
        if (tid < o) { ss[tid] += ss[tid + o]; sq[tid] += sq[tid + o]; }
        __syncthreads();
    }
    if (tid == 0) { psum[blockIdx.x] = ss[0]; psq[blockIdx.x] = sq[0]; }
}

__global__ void k_bn_finalize(const float* __restrict__ psum, const float* __restrict__ psq,
                              float* __restrict__ meanc, float* __restrict__ rstdc) {
    int c = threadIdx.x;  // 64 threads
    float s = 0.f, q = 0.f;
    for (int b = 0; b < NB; ++b)
        for (int j = 0; j < 4; ++j) {
            s += psum[(b * 64 + c) * 4 + j];
            q += psq[(b * 64 + c) * 4 + j];
        }
    const float inv = 1.f / (float)(NB * NHW);
    float m = s * inv;
    float v = q * inv - m * m;
    meanc[c] = m;
    rstdc[c] = rsqrtf(v + EPS);
}

// ---------------------------------------------------------------------------
// SE partial: s4[bc*4+q] = sum_{quarter} x2*y3 ; grid = 2048
__global__ void k_se_reduce(const float* __restrict__ x2, const float* __restrict__ y3,
                            float* __restrict__ s4) {
    __shared__ float ss[256];
    int q   = blockIdx.x & 3;
    int bc  = blockIdx.x >> 2;
    int tid = threadIdx.x;
    const float* a  = x2 + (size_t)bc * NHW + q * (NHW / 4);
    const float* b_ = y3 + (size_t)bc * NHW + q * (NHW / 4);
    float acc = 0.f;
    for (int i = tid; i < NHW / 4; i += 256) acc += a[i] * b_[i];
    ss[tid] = acc; __syncthreads();
    for (int o = 128; o > 0; o >>= 1) {
        if (tid < o) ss[tid] += ss[tid + o];
        __syncthreads();
    }
    if (tid == 0) s4[blockIdx.x] = ss[0];
}

// e[b,c] = sigmoid(W2 @ relu(W1 @ s + b1) + b2) ; one block (64 threads) per b
__global__ void k_se_mlp(const float* __restrict__ s4, const float* __restrict__ w1,
                         const float* __restrict__ b1, const float* __restrict__ w2,
                         const float* __restrict__ b2, float* __restrict__ e) {
    __shared__ float sh[64], e1[8];
    int b = blockIdx.x, tid = threadIdx.x;
    float sv = 0.f;
    #pragma unroll
    for (int j = 0; j < 4; ++j) sv += s4[(b * 64 + tid) * 4 + j];
    sh[tid] = sv * (4.f / (float)NHW);
    __syncthreads();
    if (tid < 8) {
        float a = b1[tid];
        for (int c = 0; c < 64; ++c) a += sh[c] * w1[tid * 64 + c];
        e1[tid] = a > 0.f ? a : 0.f;
    }
    __syncthreads();
    float a = b2[tid];
    #pragma unroll
    for (int j = 0; j < 8; ++j) a += e1[j] * w2[tid * 8 + j];
    e[b * 64 + tid] = 1.f / (1.f + expf(-a));
}

// out = x7 * (1 + e), x7 = 4*x2*y3
__global__ void k_final(const float* __restrict__ x2, const float* __restrict__ y3,
                        const float* __restrict__ e, float* __restrict__ out) {
    int p = blockIdx.x * 256 + threadIdx.x;
    int b = p >> 20, c = (p >> 14) & 63;
    out[p] = 4.f * x2[p] * y3[p] * (1.f + e[b * 64 + c]);
}

// ---------------------------------------------------------------------------
extern "C" void kernel_launch(void* const* d_in, const int* in_sizes, int n_in,
                              void* d_out, int out_size, void* d_ws, size_t ws_size,
                              hipStream_t stream) {
    const float* x     = (const float*)d_in[0];
    const float* fc1w  = (const float*)d_in[1];
    const float* fc1b  = (const float*)d_in[2];
    const float* fc2w  = (const float*)d_in[3];
    const float* fc2b  = (const float*)d_in[4];
    const float* fc3w  = (const float*)d_in[5];
    const float* fc3b  = (const float*)d_in[6];
    const float* fc4w  = (const float*)d_in[7];
    const float* fc4b  = (const float*)d_in[8];
    const float* fc5w  = (const float*)d_in[9];
    const float* fc5b  = (const float*)d_in[10];
    const float* lng   = (const float*)d_in[11];
    const float* lnb   = (const float*)d_in[12];
    const float* pcw   = (const float*)d_in[13];
    const float* dww   = (const float*)d_in[14];
    const float* dwb   = (const float*)d_in[15];
    const float* dwbng = (const float*)d_in[16];
    const float* dwbnb = (const float*)d_in[17];
    const float* ddw   = (const float*)d_in[18];
    const float* ddbng = (const float*)d_in[19];
    const float* ddbnb = (const float*)d_in[20];
    const float* sew1  = (const float*)d_in[21];
    const float* seb1  = (const float*)d_in[22];
    const float* sew2  = (const float*)d_in[23];
    const float* seb2  = (const float*)d_in[24];

    float* out  = (float*)d_out;
    float* ws   = (float*)d_ws;
    float* buf0 = ws;                      // xn, later x2
    float* buf1 = ws + (size_t)SZ;         // t1, x_2, d1, y3
    float* buf2 = ws + (size_t)2 * SZ;     // t2, x1, d2
    float* st   = ws + (size_t)3 * SZ;
    float* psum   = st;          // 2048
    float* psq    = st + 2048;   // 2048
    float* meanc1 = st + 4096;   // 64
    float* rstdc1 = st + 4160;   // 64
    float* meanc2 = st + 4224;   // 64
    float* rstdc2 = st + 4288;   // 64
    float* svec   = st + 4352;   // 2048
    float* evec   = st + 6400;   // 512
    float* pqv    = st + 6912;   // 128

    dim3 blk(256);
    const float* nil = nullptr;

    // xn = transpose(x)
    k_transpose<<<NB * (NHW / 64), blk, 0, stream>>>(x, buf0);
    // P,Q for folded LN
    k_pq<<<1, 64, 0, stream>>>(fc5w, lng, lnb, pqv);
    // t1 = gelu(fc1(roll_h(xn,+1)))
    k_mfc<0, true,  false, false, true, false><<<NPOS / 64, blk, 0, stream>>>(buf0, fc1w, fc1b, nil, nil, nil, nil, nil, buf1);
    // t2 = gelu(fc3(roll_w(xn,-1)))
    k_mfc<2, true,  false, false, true, false><<<NPOS / 64, blk, 0, stream>>>(buf0, fc3w, fc3b, nil, nil, nil, nil, nil, buf2);
    // x_1 = fc2(roll_w(t1,+1)) + xn   (d_out used as scratch, fully rewritten later)
    k_mfc<1, false, true,  false, true, false><<<NPOS / 64, blk, 0, stream>>>(buf1, fc2w, fc2b, buf0, nil, nil, nil, nil, out);
    // x_2 = fc4(roll_h(t2,+1)) + xn
    k_mfc<0, false, true,  false, true, false><<<NPOS / 64, blk, 0, stream>>>(buf2, fc4w, fc4b, buf0, nil, nil, nil, nil, buf1);
    // x1 = LN(concat(x_1,x_2)) @ fc5 + b5 + xn
    k_mln<<<NPOS / 64, blk, 0, stream>>>(out, buf1, fc5w, lng, pqv, fc5b, buf0, buf2);
    // x2 = pc(x1)
    k_mfc<3, false, false, true, false, false><<<NPOS / 64, blk, 0, stream>>>(buf2, pcw, nil, nil, nil, nil, nil, nil, buf0);
    // d1 = dwconv3x3(x2, dil=1) + dw_b
    k_dwconv<1, true, false><<<SZ / 256, blk, 0, stream>>>(buf0, dww, dwb, nil, nil, nil, nil, buf1);
    k_plane_stats<<<NB * NC * 4, blk, 0, stream>>>(buf1, psum, psq);
    k_bn_finalize<<<1, 64, 0, stream>>>(psum, psq, meanc1, rstdc1);
    // d2 = dwconv3x3(relu(bn1(d1)), dil=2)   [BN+relu fused into load]
    k_dwconv<2, false, true><<<SZ / 256, blk, 0, stream>>>(buf1, ddw, nil, meanc1, rstdc1, dwbng, dwbnb, buf2);
    k_plane_stats<<<NB * NC * 4, blk, 0, stream>>>(buf2, psum, psq);
    k_bn_finalize<<<1, 64, 0, stream>>>(psum, psq, meanc2, rstdc2);
    // y3 = pc(relu(bn2(d2)))                 [BN+relu fused into load]
    k_mfc<3, false, false, true, false, true><<<NPOS / 64, blk, 0, stream>>>(buf2, pcw, nil, nil, meanc2, rstdc2, ddbng, ddbnb, buf1);
    // SE + final: out = 4*x2*y3*(1+e)
    k_se_reduce<<<NB * NC * 4, blk, 0, stream>>>(buf0, buf1, svec);
    k_se_mlp<<<NB, 64, 0, stream>>>(svec, sew1, seb1, sew2, seb2, evec);
    k_final<<<SZ / 256, blk, 0, stream>>>(buf0, buf1, evec, out);
}